// Round 1
// baseline (505.334 us; speedup 1.0000x reference)
//
#include <hip/hip_runtime.h>
#include <math.h>

#define NN 50000
#define NE 800000

// ---- degree count: cnt[d] += 1 per edge ----
__global__ void k_count(const int* __restrict__ dst, int* __restrict__ cnt, int E) {
  int e = blockIdx.x * blockDim.x + threadIdx.x;
  if (e < E) atomicAdd(&cnt[dst[e]], 1);
}

// ---- dinv[i] = rsqrt(cnt[i] + 1) (self loop) ----
__global__ void k_dinv(const int* __restrict__ cnt, float* __restrict__ dinv, int n) {
  int i = blockIdx.x * blockDim.x + threadIdx.x;
  if (i < n) dinv[i] = rsqrtf((float)cnt[i] + 1.0f);
}

// ---- block-level inclusive scan of cnt -> rp[i+1]; block sums -> bsum ----
__global__ void k_scan_block(const int* __restrict__ cnt, int* __restrict__ rp,
                             int* __restrict__ bsum, int n) {
  __shared__ int s[1024];
  int tid = threadIdx.x;
  int i = blockIdx.x * 1024 + tid;
  int v = (i < n) ? cnt[i] : 0;
  s[tid] = v;
  __syncthreads();
  for (int off = 1; off < 1024; off <<= 1) {
    int t = (tid >= off) ? s[tid - off] : 0;
    __syncthreads();
    s[tid] += t;
    __syncthreads();
  }
  if (i < n) rp[i + 1] = s[tid];
  if (i == 0) rp[0] = 0;
  if (tid == 1023) bsum[blockIdx.x] = s[1023];
}

// ---- exclusive scan of block sums in place (nb <= 64) ----
__global__ void k_scan_bsum(int* __restrict__ bsum, int nb) {
  __shared__ int s[64];
  int t = threadIdx.x;
  int v = (t < nb) ? bsum[t] : 0;
  s[t] = v;
  __syncthreads();
  for (int off = 1; off < 64; off <<= 1) {
    int x = (t >= off) ? s[t - off] : 0;
    __syncthreads();
    s[t] += x;
    __syncthreads();
  }
  if (t < nb) bsum[t] = s[t] - v;  // exclusive
}

// ---- add block offsets ----
__global__ void k_scan_add(int* __restrict__ rp, const int* __restrict__ bsum, int n) {
  int i = blockIdx.x * 1024 + threadIdx.x;
  if (i < n) rp[i + 1] += bsum[blockIdx.x];
}

// ---- scatter edges into CSR: col[pos]=src, wsrc[pos]=dinv[src] ----
__global__ void k_scatter(const int* __restrict__ src, const int* __restrict__ dst,
                          const int* __restrict__ rp, int* __restrict__ cur,
                          const float* __restrict__ dinv, int* __restrict__ col,
                          float* __restrict__ wsrc, int E) {
  int e = blockIdx.x * blockDim.x + threadIdx.x;
  if (e >= E) return;
  int d = dst[e], s = src[e];
  int pos = rp[d] + atomicAdd(&cur[d], 1);
  col[pos] = s;
  wsrc[pos] = dinv[s];
}

// ---- H = X @ W  (row-major, fp32 VALU). thread = (row, 4-channel group) ----
template <int CIN, int COUT>
__global__ __launch_bounds__(256) void k_gemm(const float* __restrict__ X,
                                              const float* __restrict__ W,
                                              float* __restrict__ H, int n) {
  const int CHG = COUT / 4;
  int t = blockIdx.x * 256 + threadIdx.x;
  int row = t / CHG;
  int chg = t % CHG;
  if (row >= n) return;
  int ch = chg * 4;
  const float* xr = X + (size_t)row * CIN;
  float4 acc = make_float4(0.f, 0.f, 0.f, 0.f);
#pragma unroll 4
  for (int k = 0; k < CIN; k += 4) {
    float4 xv = *(const float4*)(xr + k);
    float4 w0 = *(const float4*)(W + (size_t)(k + 0) * COUT + ch);
    float4 w1 = *(const float4*)(W + (size_t)(k + 1) * COUT + ch);
    float4 w2 = *(const float4*)(W + (size_t)(k + 2) * COUT + ch);
    float4 w3 = *(const float4*)(W + (size_t)(k + 3) * COUT + ch);
    acc.x += xv.x * w0.x + xv.y * w1.x + xv.z * w2.x + xv.w * w3.x;
    acc.y += xv.x * w0.y + xv.y * w1.y + xv.z * w2.y + xv.w * w3.y;
    acc.z += xv.x * w0.z + xv.y * w1.z + xv.z * w2.z + xv.w * w3.z;
    acc.w += xv.x * w0.w + xv.y * w1.w + xv.z * w2.w + xv.w * w3.w;
  }
  *(float4*)(H + (size_t)row * COUT + ch) = acc;
}

// ---- gather-aggregate: out = relu(dinv[i]*(sum_s h[s]*dinv[s] + h[i]*dinv[i]) + b) ----
template <int COUT>
__global__ __launch_bounds__(256) void k_agg(const float* __restrict__ H,
                                             const int* __restrict__ col,
                                             const float* __restrict__ wsrc,
                                             const int* __restrict__ rp,
                                             const float* __restrict__ dinv,
                                             const float* __restrict__ bias,
                                             float* __restrict__ out, int n) {
  const int NPB = 256 / COUT;
  int node = blockIdx.x * NPB + threadIdx.x / COUT;
  int ch = threadIdx.x % COUT;
  if (node >= n) return;
  float di = dinv[node];
  float acc = H[(size_t)node * COUT + ch] * di;  // self loop term
  int j = rp[node];
  int end = rp[node + 1];
  for (; j < end; ++j) {
    int s = col[j];
    float w = wsrc[j];
    acc += H[(size_t)s * COUT + ch] * w;
  }
  float v = acc * di + bias[ch];
  out[(size_t)node * COUT + ch] = v > 0.f ? v : 0.f;
}

extern "C" void kernel_launch(void* const* d_in, const int* in_sizes, int n_in,
                              void* d_out, int out_size, void* d_ws, size_t ws_size,
                              hipStream_t stream) {
  const float* x  = (const float*)d_in[0];
  const int*   ei = (const int*)d_in[1];
  const float* W1 = (const float*)d_in[2];
  const float* b1 = (const float*)d_in[3];
  const float* W2 = (const float*)d_in[4];
  const float* b2 = (const float*)d_in[5];
  float* out = (float*)d_out;

  const int N = NN, E = NE;
  const int* src = ei;      // edge_index[0]
  const int* dst = ei + E;  // edge_index[1]

  char* ws = (char*)d_ws;
  size_t off = 0;
  auto carve = [&](size_t bytes) -> void* {
    void* p = ws + off;
    off = (off + bytes + 255) & ~(size_t)255;
    return p;
  };
  int*   cnt  = (int*)carve((size_t)N * 4);
  float* dinv = (float*)carve((size_t)N * 4);
  int*   rp   = (int*)carve((size_t)(N + 1) * 4);
  int*   bsum = (int*)carve(64 * 4);
  int*   cur  = (int*)carve((size_t)N * 4);
  int*   col  = (int*)carve((size_t)E * 4);
  float* wsrc = (float*)carve((size_t)E * 4);
  float* H1   = (float*)carve((size_t)N * 128 * 4);
  float* A1   = (float*)carve((size_t)N * 128 * 4);
  float* H2   = (float*)carve((size_t)N * 64 * 4);

  hipMemsetAsync(cnt, 0, (size_t)N * 4, stream);
  hipMemsetAsync(cur, 0, (size_t)N * 4, stream);

  k_count<<<(E + 255) / 256, 256, 0, stream>>>(dst, cnt, E);
  k_dinv<<<(N + 255) / 256, 256, 0, stream>>>(cnt, dinv, N);

  const int SB = (N + 1023) / 1024;  // 49
  k_scan_block<<<SB, 1024, 0, stream>>>(cnt, rp, bsum, N);
  k_scan_bsum<<<1, 64, 0, stream>>>(bsum, SB);
  k_scan_add<<<SB, 1024, 0, stream>>>(rp, bsum, N);

  k_scatter<<<(E + 255) / 256, 256, 0, stream>>>(src, dst, rp, cur, dinv, col, wsrc, E);

  // layer 1: H1 = x @ W1 ; A1 = relu(agg(H1) + b1)
  k_gemm<128, 128><<<(N * 32 + 255) / 256, 256, 0, stream>>>(x, W1, H1, N);
  k_agg<128><<<(N + 1) / 2, 256, 0, stream>>>(H1, col, wsrc, rp, dinv, b1, A1, N);

  // layer 2: H2 = A1 @ W2 ; out = relu(agg(H2) + b2)
  k_gemm<128, 64><<<(N * 16 + 255) / 256, 256, 0, stream>>>(A1, W2, H2, N);
  k_agg<64><<<(N + 3) / 4, 256, 0, stream>>>(H2, col, wsrc, rp, dinv, b2, out, N);
}

// Round 2
// 372.097 us; speedup vs baseline: 1.3581x; 1.3581x over previous
//
#include <hip/hip_runtime.h>
#include <math.h>

#define NN 50000
#define NE 800000

// ---- degree count: cnt[d] += 1 per edge ----
__global__ void k_count(const int* __restrict__ dst, int* __restrict__ cnt, int E) {
  int e = blockIdx.x * blockDim.x + threadIdx.x;
  if (e < E) atomicAdd(&cnt[dst[e]], 1);
}

// ---- dinv[i] = rsqrt(cnt[i] + 1) (self loop) ----
__global__ void k_dinv(const int* __restrict__ cnt, float* __restrict__ dinv, int n) {
  int i = blockIdx.x * blockDim.x + threadIdx.x;
  if (i < n) dinv[i] = rsqrtf((float)cnt[i] + 1.0f);
}

// ---- block-level inclusive scan of cnt -> rp[i+1]; block sums -> bsum ----
__global__ void k_scan_block(const int* __restrict__ cnt, int* __restrict__ rp,
                             int* __restrict__ bsum, int n) {
  __shared__ int s[1024];
  int tid = threadIdx.x;
  int i = blockIdx.x * 1024 + tid;
  int v = (i < n) ? cnt[i] : 0;
  s[tid] = v;
  __syncthreads();
  for (int off = 1; off < 1024; off <<= 1) {
    int t = (tid >= off) ? s[tid - off] : 0;
    __syncthreads();
    s[tid] += t;
    __syncthreads();
  }
  if (i < n) rp[i + 1] = s[tid];
  if (i == 0) rp[0] = 0;
  if (tid == 1023) bsum[blockIdx.x] = s[1023];
}

// ---- exclusive scan of block sums in place (nb <= 64) ----
__global__ void k_scan_bsum(int* __restrict__ bsum, int nb) {
  __shared__ int s[64];
  int t = threadIdx.x;
  int v = (t < nb) ? bsum[t] : 0;
  s[t] = v;
  __syncthreads();
  for (int off = 1; off < 64; off <<= 1) {
    int x = (t >= off) ? s[t - off] : 0;
    __syncthreads();
    s[t] += x;
    __syncthreads();
  }
  if (t < nb) bsum[t] = s[t] - v;  // exclusive
}

// ---- add block offsets ----
__global__ void k_scan_add(int* __restrict__ rp, const int* __restrict__ bsum, int n) {
  int i = blockIdx.x * 1024 + threadIdx.x;
  if (i < n) rp[i + 1] += bsum[blockIdx.x];
}

// ---- scatter edges into CSR: col[pos]=src, wsrc[pos]=dinv[src] ----
__global__ void k_scatter(const int* __restrict__ src, const int* __restrict__ dst,
                          const int* __restrict__ rp, int* __restrict__ cur,
                          const float* __restrict__ dinv, int* __restrict__ col,
                          float* __restrict__ wsrc, int E) {
  int e = blockIdx.x * blockDim.x + threadIdx.x;
  if (e >= E) return;
  int d = dst[e], s = src[e];
  int pos = rp[d] + atomicAdd(&cur[d], 1);
  col[pos] = s;
  wsrc[pos] = dinv[s];
}

// ---- H = X @ W  (row-major, fp32 VALU). thread = (row, 4-channel group) ----
template <int CIN, int COUT>
__global__ __launch_bounds__(256) void k_gemm(const float* __restrict__ X,
                                              const float* __restrict__ W,
                                              float* __restrict__ H, int n) {
  const int CHG = COUT / 4;
  int t = blockIdx.x * 256 + threadIdx.x;
  int row = t / CHG;
  int chg = t % CHG;
  if (row >= n) return;
  int ch = chg * 4;
  const float* xr = X + (size_t)row * CIN;
  float4 acc = make_float4(0.f, 0.f, 0.f, 0.f);
#pragma unroll 4
  for (int k = 0; k < CIN; k += 4) {
    float4 xv = *(const float4*)(xr + k);
    float4 w0 = *(const float4*)(W + (size_t)(k + 0) * COUT + ch);
    float4 w1 = *(const float4*)(W + (size_t)(k + 1) * COUT + ch);
    float4 w2 = *(const float4*)(W + (size_t)(k + 2) * COUT + ch);
    float4 w3 = *(const float4*)(W + (size_t)(k + 3) * COUT + ch);
    acc.x += xv.x * w0.x + xv.y * w1.x + xv.z * w2.x + xv.w * w3.x;
    acc.y += xv.x * w0.y + xv.y * w1.y + xv.z * w2.y + xv.w * w3.y;
    acc.z += xv.x * w0.z + xv.y * w1.z + xv.z * w2.z + xv.w * w3.z;
    acc.w += xv.x * w0.w + xv.y * w1.w + xv.z * w2.w + xv.w * w3.w;
  }
  *(float4*)(H + (size_t)row * COUT + ch) = acc;
}

// ---- gather-aggregate, float4 per thread, 4-deep edge unroll ----
// out = relu(dinv[i]*(sum_s h[s]*dinv[s] + h[i]*dinv[i]) + b)
template <int COUT>
__global__ __launch_bounds__(256) void k_agg(const float* __restrict__ H,
                                             const int* __restrict__ col,
                                             const float* __restrict__ wsrc,
                                             const int* __restrict__ rp,
                                             const float* __restrict__ dinv,
                                             const float* __restrict__ bias,
                                             float* __restrict__ out, int n) {
  const int TPN = COUT / 4;        // threads per node (32 or 16)
  const int NPB = 256 / TPN;       // nodes per block (8 or 16)
  int node = blockIdx.x * NPB + threadIdx.x / TPN;
  int cg = (threadIdx.x % TPN) * 4;
  if (node >= n) return;
  float di = dinv[node];
  float4 h = *(const float4*)(H + (size_t)node * COUT + cg);
  float4 acc = make_float4(h.x * di, h.y * di, h.z * di, h.w * di);  // self loop
  int j = rp[node];
  int end = rp[node + 1];
  for (; j + 4 <= end; j += 4) {
    int s0 = col[j + 0], s1 = col[j + 1], s2 = col[j + 2], s3 = col[j + 3];
    float w0 = wsrc[j + 0], w1 = wsrc[j + 1], w2 = wsrc[j + 2], w3 = wsrc[j + 3];
    float4 a = *(const float4*)(H + (size_t)s0 * COUT + cg);
    float4 b = *(const float4*)(H + (size_t)s1 * COUT + cg);
    float4 c = *(const float4*)(H + (size_t)s2 * COUT + cg);
    float4 d = *(const float4*)(H + (size_t)s3 * COUT + cg);
    acc.x += a.x * w0 + b.x * w1 + c.x * w2 + d.x * w3;
    acc.y += a.y * w0 + b.y * w1 + c.y * w2 + d.y * w3;
    acc.z += a.z * w0 + b.z * w1 + c.z * w2 + d.z * w3;
    acc.w += a.w * w0 + b.w * w1 + c.w * w2 + d.w * w3;
  }
  for (; j < end; ++j) {
    int s = col[j];
    float w = wsrc[j];
    float4 a = *(const float4*)(H + (size_t)s * COUT + cg);
    acc.x += a.x * w;
    acc.y += a.y * w;
    acc.z += a.z * w;
    acc.w += a.w * w;
  }
  float4 bv = *(const float4*)(bias + cg);
  float4 r;
  r.x = acc.x * di + bv.x;
  r.y = acc.y * di + bv.y;
  r.z = acc.z * di + bv.z;
  r.w = acc.w * di + bv.w;
  r.x = r.x > 0.f ? r.x : 0.f;
  r.y = r.y > 0.f ? r.y : 0.f;
  r.z = r.z > 0.f ? r.z : 0.f;
  r.w = r.w > 0.f ? r.w : 0.f;
  *(float4*)(out + (size_t)node * COUT + cg) = r;
}

extern "C" void kernel_launch(void* const* d_in, const int* in_sizes, int n_in,
                              void* d_out, int out_size, void* d_ws, size_t ws_size,
                              hipStream_t stream) {
  const float* x  = (const float*)d_in[0];
  const int*   ei = (const int*)d_in[1];
  const float* W1 = (const float*)d_in[2];
  const float* b1 = (const float*)d_in[3];
  const float* W2 = (const float*)d_in[4];
  const float* b2 = (const float*)d_in[5];
  float* out = (float*)d_out;

  const int N = NN, E = NE;
  const int* src = ei;      // edge_index[0]
  const int* dst = ei + E;  // edge_index[1]

  char* ws = (char*)d_ws;
  size_t off = 0;
  auto carve = [&](size_t bytes) -> void* {
    void* p = ws + off;
    off = (off + bytes + 255) & ~(size_t)255;
    return p;
  };
  int*   cnt  = (int*)carve((size_t)N * 4);
  float* dinv = (float*)carve((size_t)N * 4);
  int*   rp   = (int*)carve((size_t)(N + 1) * 4);
  int*   bsum = (int*)carve(64 * 4);
  int*   cur  = (int*)carve((size_t)N * 4);
  int*   col  = (int*)carve((size_t)E * 4);
  float* wsrc = (float*)carve((size_t)E * 4);
  float* H1   = (float*)carve((size_t)N * 128 * 4);
  float* A1   = (float*)carve((size_t)N * 128 * 4);
  float* H2   = (float*)carve((size_t)N * 64 * 4);

  hipMemsetAsync(cnt, 0, (size_t)N * 4, stream);
  hipMemsetAsync(cur, 0, (size_t)N * 4, stream);

  k_count<<<(E + 255) / 256, 256, 0, stream>>>(dst, cnt, E);
  k_dinv<<<(N + 255) / 256, 256, 0, stream>>>(cnt, dinv, N);

  const int SB = (N + 1023) / 1024;  // 49
  k_scan_block<<<SB, 1024, 0, stream>>>(cnt, rp, bsum, N);
  k_scan_bsum<<<1, 64, 0, stream>>>(bsum, SB);
  k_scan_add<<<SB, 1024, 0, stream>>>(rp, bsum, N);

  k_scatter<<<(E + 255) / 256, 256, 0, stream>>>(src, dst, rp, cur, dinv, col, wsrc, E);

  // layer 1: H1 = x @ W1 ; A1 = relu(agg(H1) + b1)
  k_gemm<128, 128><<<(N * 32 + 255) / 256, 256, 0, stream>>>(x, W1, H1, N);
  k_agg<128><<<(N + 7) / 8, 256, 0, stream>>>(H1, col, wsrc, rp, dinv, b1, A1, N);

  // layer 2: H2 = A1 @ W2 ; out = relu(agg(H2) + b2)
  k_gemm<128, 64><<<(N * 16 + 255) / 256, 256, 0, stream>>>(A1, W2, H2, N);
  k_agg<64><<<(N + 15) / 16, 256, 0, stream>>>(H2, col, wsrc, rp, dinv, b2, out, N);
}

// Round 3
// 259.789 us; speedup vs baseline: 1.9452x; 1.4323x over previous
//
#include <hip/hip_runtime.h>
#include <math.h>

#define NN 50000
#define NE 800000

// ---- degree count: cnt[d] += 1 per edge ----
__global__ void k_count(const int* __restrict__ dst, int* __restrict__ cnt, int E) {
  int e = blockIdx.x * blockDim.x + threadIdx.x;
  if (e < E) atomicAdd(&cnt[dst[e]], 1);
}

// ---- dinv[i] = rsqrt(cnt[i] + 1) (self loop) ----
__global__ void k_dinv(const int* __restrict__ cnt, float* __restrict__ dinv, int n) {
  int i = blockIdx.x * blockDim.x + threadIdx.x;
  if (i < n) dinv[i] = rsqrtf((float)cnt[i] + 1.0f);
}

// ---- block-level inclusive scan of cnt -> rp[i+1]; block sums -> bsum ----
__global__ void k_scan_block(const int* __restrict__ cnt, int* __restrict__ rp,
                             int* __restrict__ bsum, int n) {
  __shared__ int s[1024];
  int tid = threadIdx.x;
  int i = blockIdx.x * 1024 + tid;
  int v = (i < n) ? cnt[i] : 0;
  s[tid] = v;
  __syncthreads();
  for (int off = 1; off < 1024; off <<= 1) {
    int t = (tid >= off) ? s[tid - off] : 0;
    __syncthreads();
    s[tid] += t;
    __syncthreads();
  }
  if (i < n) rp[i + 1] = s[tid];
  if (i == 0) rp[0] = 0;
  if (tid == 1023) bsum[blockIdx.x] = s[1023];
}

// ---- exclusive scan of block sums in place (nb <= 64) ----
__global__ void k_scan_bsum(int* __restrict__ bsum, int nb) {
  __shared__ int s[64];
  int t = threadIdx.x;
  int v = (t < nb) ? bsum[t] : 0;
  s[t] = v;
  __syncthreads();
  for (int off = 1; off < 64; off <<= 1) {
    int x = (t >= off) ? s[t - off] : 0;
    __syncthreads();
    s[t] += x;
    __syncthreads();
  }
  if (t < nb) bsum[t] = s[t] - v;  // exclusive
}

// ---- add block offsets ----
__global__ void k_scan_add(int* __restrict__ rp, const int* __restrict__ bsum, int n) {
  int i = blockIdx.x * 1024 + threadIdx.x;
  if (i < n) rp[i + 1] += bsum[blockIdx.x];
}

// ---- scatter edges into CSR: col[pos]=src, wsrc[pos]=dinv[src] ----
__global__ void k_scatter(const int* __restrict__ src, const int* __restrict__ dst,
                          const int* __restrict__ rp, int* __restrict__ cur,
                          const float* __restrict__ dinv, int* __restrict__ col,
                          float* __restrict__ wsrc, int E) {
  int e = blockIdx.x * blockDim.x + threadIdx.x;
  if (e >= E) return;
  int d = dst[e], s = src[e];
  int pos = rp[d] + atomicAdd(&cur[d], 1);
  col[pos] = s;
  wsrc[pos] = dinv[s];
}

// ---- H = X @ W, register-tiled: thread = 8 rows x 4 cols (32 acc) ----
// W bytes/FMA = 0.5 (amortized over 8 rows); x loads broadcast within wave.
template <int CIN, int COUT>
__global__ __launch_bounds__(256) void k_gemm(const float* __restrict__ X,
                                              const float* __restrict__ W,
                                              float* __restrict__ H, int n) {
  constexpr int CG = COUT / 4;     // column groups (32 or 16)
  constexpr int RGPB = 256 / CG;   // row groups per block (8 or 16)
  int tid = threadIdx.x;
  int cg = tid % CG;
  int rg = tid / CG;
  int row0 = (blockIdx.x * RGPB + rg) * 8;
  if (row0 >= n) return;           // N % 8 == 0, full 8-row groups only
  int ch = cg * 4;
  const float* xr = X + (size_t)row0 * CIN;

  float4 acc[8];
#pragma unroll
  for (int r = 0; r < 8; ++r) acc[r] = make_float4(0.f, 0.f, 0.f, 0.f);

  for (int k = 0; k < CIN; k += 4) {
    float4 w0 = *(const float4*)(W + (size_t)(k + 0) * COUT + ch);
    float4 w1 = *(const float4*)(W + (size_t)(k + 1) * COUT + ch);
    float4 w2 = *(const float4*)(W + (size_t)(k + 2) * COUT + ch);
    float4 w3 = *(const float4*)(W + (size_t)(k + 3) * COUT + ch);
#pragma unroll
    for (int r = 0; r < 8; ++r) {
      float4 xv = *(const float4*)(xr + (size_t)r * CIN + k);
      acc[r].x += xv.x * w0.x + xv.y * w1.x + xv.z * w2.x + xv.w * w3.x;
      acc[r].y += xv.x * w0.y + xv.y * w1.y + xv.z * w2.y + xv.w * w3.y;
      acc[r].z += xv.x * w0.z + xv.y * w1.z + xv.z * w2.z + xv.w * w3.z;
      acc[r].w += xv.x * w0.w + xv.y * w1.w + xv.z * w2.w + xv.w * w3.w;
    }
  }
#pragma unroll
  for (int r = 0; r < 8; ++r)
    *(float4*)(H + (size_t)(row0 + r) * COUT + ch) = acc[r];
}

// ---- gather-aggregate, float4 per thread, 4-deep edge unroll ----
// out = relu(dinv[i]*(sum_s h[s]*dinv[s] + h[i]*dinv[i]) + b)
template <int COUT>
__global__ __launch_bounds__(256) void k_agg(const float* __restrict__ H,
                                             const int* __restrict__ col,
                                             const float* __restrict__ wsrc,
                                             const int* __restrict__ rp,
                                             const float* __restrict__ dinv,
                                             const float* __restrict__ bias,
                                             float* __restrict__ out, int n) {
  const int TPN = COUT / 4;        // threads per node (32 or 16)
  const int NPB = 256 / TPN;       // nodes per block (8 or 16)
  int node = blockIdx.x * NPB + threadIdx.x / TPN;
  int cg = (threadIdx.x % TPN) * 4;
  if (node >= n) return;
  float di = dinv[node];
  float4 h = *(const float4*)(H + (size_t)node * COUT + cg);
  float4 acc = make_float4(h.x * di, h.y * di, h.z * di, h.w * di);  // self loop
  int j = rp[node];
  int end = rp[node + 1];
  for (; j + 4 <= end; j += 4) {
    int s0 = col[j + 0], s1 = col[j + 1], s2 = col[j + 2], s3 = col[j + 3];
    float w0 = wsrc[j + 0], w1 = wsrc[j + 1], w2 = wsrc[j + 2], w3 = wsrc[j + 3];
    float4 a = *(const float4*)(H + (size_t)s0 * COUT + cg);
    float4 b = *(const float4*)(H + (size_t)s1 * COUT + cg);
    float4 c = *(const float4*)(H + (size_t)s2 * COUT + cg);
    float4 d = *(const float4*)(H + (size_t)s3 * COUT + cg);
    acc.x += a.x * w0 + b.x * w1 + c.x * w2 + d.x * w3;
    acc.y += a.y * w0 + b.y * w1 + c.y * w2 + d.y * w3;
    acc.z += a.z * w0 + b.z * w1 + c.z * w2 + d.z * w3;
    acc.w += a.w * w0 + b.w * w1 + c.w * w2 + d.w * w3;
  }
  for (; j < end; ++j) {
    int s = col[j];
    float w = wsrc[j];
    float4 a = *(const float4*)(H + (size_t)s * COUT + cg);
    acc.x += a.x * w;
    acc.y += a.y * w;
    acc.z += a.z * w;
    acc.w += a.w * w;
  }
  float4 bv = *(const float4*)(bias + cg);
  float4 r;
  r.x = acc.x * di + bv.x;
  r.y = acc.y * di + bv.y;
  r.z = acc.z * di + bv.z;
  r.w = acc.w * di + bv.w;
  r.x = r.x > 0.f ? r.x : 0.f;
  r.y = r.y > 0.f ? r.y : 0.f;
  r.z = r.z > 0.f ? r.z : 0.f;
  r.w = r.w > 0.f ? r.w : 0.f;
  *(float4*)(out + (size_t)node * COUT + cg) = r;
}

extern "C" void kernel_launch(void* const* d_in, const int* in_sizes, int n_in,
                              void* d_out, int out_size, void* d_ws, size_t ws_size,
                              hipStream_t stream) {
  const float* x  = (const float*)d_in[0];
  const int*   ei = (const int*)d_in[1];
  const float* W1 = (const float*)d_in[2];
  const float* b1 = (const float*)d_in[3];
  const float* W2 = (const float*)d_in[4];
  const float* b2 = (const float*)d_in[5];
  float* out = (float*)d_out;

  const int N = NN, E = NE;
  const int* src = ei;      // edge_index[0]
  const int* dst = ei + E;  // edge_index[1]

  char* ws = (char*)d_ws;
  size_t off = 0;
  auto carve = [&](size_t bytes) -> void* {
    void* p = ws + off;
    off = (off + bytes + 255) & ~(size_t)255;
    return p;
  };
  int*   cnt  = (int*)carve((size_t)N * 4);
  float* dinv = (float*)carve((size_t)N * 4);
  int*   rp   = (int*)carve((size_t)(N + 1) * 4);
  int*   bsum = (int*)carve(64 * 4);
  int*   cur  = (int*)carve((size_t)N * 4);
  int*   col  = (int*)carve((size_t)E * 4);
  float* wsrc = (float*)carve((size_t)E * 4);
  float* H1   = (float*)carve((size_t)N * 128 * 4);
  float* A1   = (float*)carve((size_t)N * 128 * 4);
  float* H2   = (float*)carve((size_t)N * 64 * 4);

  hipMemsetAsync(cnt, 0, (size_t)N * 4, stream);
  hipMemsetAsync(cur, 0, (size_t)N * 4, stream);

  k_count<<<(E + 255) / 256, 256, 0, stream>>>(dst, cnt, E);
  k_dinv<<<(N + 255) / 256, 256, 0, stream>>>(cnt, dinv, N);

  const int SB = (N + 1023) / 1024;  // 49
  k_scan_block<<<SB, 1024, 0, stream>>>(cnt, rp, bsum, N);
  k_scan_bsum<<<1, 64, 0, stream>>>(bsum, SB);
  k_scan_add<<<SB, 1024, 0, stream>>>(rp, bsum, N);

  k_scatter<<<(E + 255) / 256, 256, 0, stream>>>(src, dst, rp, cur, dinv, col, wsrc, E);

  const int RG = N / 8;  // 6250 row groups of 8
  // layer 1: H1 = x @ W1 ; A1 = relu(agg(H1) + b1)
  k_gemm<128, 128><<<(RG + 7) / 8, 256, 0, stream>>>(x, W1, H1, N);
  k_agg<128><<<(N + 7) / 8, 256, 0, stream>>>(H1, col, wsrc, rp, dinv, b1, A1, N);

  // layer 2: H2 = A1 @ W2 ; out = relu(agg(H2) + b2)
  k_gemm<128, 64><<<(RG + 15) / 16, 256, 0, stream>>>(A1, W2, H2, N);
  k_agg<64><<<(N + 15) / 16, 256, 0, stream>>>(H2, col, wsrc, rp, dinv, b2, out, N);
}